// Round 7
// baseline (164.695 us; speedup 1.0000x reference)
//
#include <hip/hip_runtime.h>
#include <math.h>

#define BB 8
#define CC 64
#define OO 64
#define HH 128
#define WW 128
#define HW (HH*WW)              // 16384
#define NPIX (BB*HW)            // 131072

typedef __bf16 bf16x8 __attribute__((ext_vector_type(8)));
typedef float floatx4 __attribute__((ext_vector_type(4)));
typedef float f32x2 __attribute__((ext_vector_type(2)));
typedef unsigned short ushort_t;

// Workspace layout (bytes) — kept identical to prior rounds (om slot now unused):
//  xt : bf16 NHWC [B][H][W][64]        16777216
//  om : (unused after fusion)          14680064
//  wt : bf16 [64][576]  (o, tap*64+c)     73728
//  wb : bf16 [32][576]  (o27pad, k)       36864
#define XT_BYTES  16777216
#define OM_BYTES  14680064
#define WT_BYTES  73728

__device__ __forceinline__ unsigned short f2b(float f) {
    unsigned u = __float_as_uint(f);
    u += 0x7fffu + ((u >> 16) & 1u);       // round-to-nearest-even
    return (unsigned short)(u >> 16);
}

// packed 2xf32 -> 2xbf16 in one VALU op (no builtin on gfx950; asm per guide)
__device__ __forceinline__ unsigned cvt_pk_bf16(float lo, float hi) {
    unsigned r;
    asm("v_cvt_pk_bf16_f32 %0, %1, %2" : "=v"(r) : "v"(lo), "v"(hi));
    return r;
}

__device__ __forceinline__ f32x2 pk_fma(f32x2 a, f32x2 b, f32x2 c) {
    f32x2 d;
    asm("v_pk_fma_f32 %0, %1, %2, %3" : "=v"(d) : "v"(a), "v"(b), "v"(c));
    return d;
}

__device__ __forceinline__ f32x2 pk_mul(f32x2 a, f32x2 b) {
    f32x2 d;
    asm("v_pk_mul_f32 %0, %1, %2" : "=v"(d) : "v"(a), "v"(b));
    return d;
}

// ---------------------------------------------------------------------------
// Kernel 1: FUSED prep — transpose (blocks 0..4095) + weight repack (4096..)
// One launch instead of two (saves a launch gap).
// ---------------------------------------------------------------------------
__global__ __launch_bounds__(256) void prep_kernel(
    const float* __restrict__ x,
    const float* __restrict__ wm, const float* __restrict__ woff,
    const float* __restrict__ wmask,
    ushort_t* __restrict__ xt, ushort_t* __restrict__ wt,
    ushort_t* __restrict__ wb)
{
    __shared__ float tile[64][33];
    int bid = blockIdx.x;
    int t   = threadIdx.x;

    if (bid < 4096) {
        // ---- transpose: NCHW fp32 -> NHWC bf16 ----
        int bh = bid >> 2;
        int w0 = (bid & 3) * 32;
        int b  = bh >> 7;
        int h  = bh & 127;
        int tx = t & 31;
        int ty = t >> 5;

        #pragma unroll
        for (int j = 0; j < 8; ++j) {
            int c = ty * 8 + j;
            tile[c][tx] = x[(((size_t)(b*CC + c))*HH + h)*WW + (w0 + tx)];
        }
        __syncthreads();
        #pragma unroll
        for (int j = 0; j < 4; ++j) {
            int w  = ty + 8*j;
            int cp = tx;
            unsigned u = cvt_pk_bf16(tile[2*cp][w], tile[2*cp+1][w]);
            *(unsigned*)(xt + (((size_t)(b*HH + h))*WW + (w0 + w))*CC + 2*cp) = u;
        }
    } else {
        // ---- weight repack to bf16 ----
        int i = (bid - 4096) * 256 + t;
        if (i < 36864) {
            int o = i / 576, k = i % 576, tap = k >> 6, c = k & 63;
            wt[i] = f2b(wm[o*576 + c*9 + tap]);
        }
        int j = i - 36864;
        if (j >= 0 && j < 18432) {
            int o = j / 576, k = j % 576, tap = k >> 6, c = k & 63;
            float v = 0.f;
            if (o < 18)      v = woff[o*576 + c*9 + tap];
            else if (o < 27) v = wmask[(o-18)*576 + c*9 + tap];
            wb[j] = f2b(v);
        }
    }
}

// ---------------------------------------------------------------------------
// Kernel 2: FUSED conv27 + deformable sampling + bf16 MFMA GEMM
//
// Round-7 change: the separate conv27 kernel (full halo staging + 14.7MB om
// write) and deform's 14.7MB om read + one launch gap are all deleted.
// Each 8x8-tile block now computes its own 27 offset/mask channels:
//   stage 10x10x64 halo (14.4KB, aliased into samp which is dead here)
//   -> 36 MFMAs/wave vs wb (36KB, L2-resident)  [rides deform's stall cycles]
//   -> epilogue (bias/sigmoid) into om_lds[64][28] (7.2KB)
//   -> barrier -> round-5 deform body verbatim, omp pointing at om_lds.
// Conv M-mapping rederived for 8x8 tiles: A-row n <-> pixel p=wv*16+n
// (win[(p>>3)+tr][(p&7)+tc]); D-row quad*4+r <-> pixel wv*16+quad*4+r.
// B-fragment identical to verified conv27 (lane n -> wb row n / 16+n).
// LDS total: 25600 (samp) + 7168 (om_lds) = 32768 B -> ~4-5 blocks/CU.
// ---------------------------------------------------------------------------
#define SROW 200   // ushorts per pixel row: 3 taps * 64 ch + 8 pad
#define WROW 72    // conv halo row pad (as in verified conv27)

__global__ __launch_bounds__(256, 4) void conv_deform_kernel(
    const ushort_t* __restrict__ xt, const ushort_t* __restrict__ wb,
    const float* __restrict__ boff, const float* __restrict__ bmsk,
    const ushort_t* __restrict__ wt, float* __restrict__ out)
{
    __shared__ ushort_t samp[64*SROW];   // 25600 B; first 14400 B alias the conv halo
    __shared__ float om_lds[64][28];     // 7168 B

    ushort_t* win = samp;                // [100][WROW] during conv phase only

    int t = threadIdx.x;
    int lane = t & 63, wv = t >> 6;
    int bid = blockIdx.x;
    int b  = bid >> 8;
    int th = (bid >> 4) & 15;
    int tw = bid & 15;
    int h0 = th * 8, w0 = tw * 8;

    const ushort_t* xbase = xt + ((size_t)b << 20);
    int n = lane & 15, quad = lane >> 4;

    // ---------------- conv phase: stage 10x10 halo ----------------
    for (int idx = t; idx < 800; idx += 256) {
        int cell = idx >> 3;             // 0..99
        int ch   = (idx & 7) << 3;
        int cy = cell / 10, cx = cell - cy*10;
        int y = h0 + cy - 1, xx = w0 + cx - 1;
        uint4 val = make_uint4(0,0,0,0);
        if ((unsigned)y < (unsigned)HH && (unsigned)xx < (unsigned)WW)
            val = *(const uint4*)(xbase + (((y << 7) + xx) << 6) + ch);
        *(uint4*)(win + cell*WROW + ch) = val;
    }
    __syncthreads();

    // ---------------- conv phase: 16 px x 32 outputs per wave ----------------
    {
        int p   = wv*16 + n;             // A-row n <-> pixel p
        int cph = p >> 3, cpw = p & 7;
        const ushort_t* wb0 = wb + n*576;
        const ushort_t* wb1 = wb + (16 + n)*576;
        floatx4 c0 = (floatx4){0.f,0.f,0.f,0.f};
        floatx4 c1 = (floatx4){0.f,0.f,0.f,0.f};

        #pragma unroll
        for (int s = 0; s < 18; ++s) {
            int tap  = s >> 1;
            int tr   = tap / 3, tc = tap % 3;
            int coff = (s & 1)*32 + quad*8;
            bf16x8 b0 = *(const bf16x8*)(wb0 + tap*64 + coff);
            bf16x8 b1 = *(const bf16x8*)(wb1 + tap*64 + coff);
            bf16x8 a  = *(const bf16x8*)(win + ((cph + tr)*10 + (cpw + tc))*WROW + coff);
            c0 = __builtin_amdgcn_mfma_f32_16x16x32_bf16(a, b0, c0, 0, 0, 0);
            c1 = __builtin_amdgcn_mfma_f32_16x16x32_bf16(a, b1, c1, 0, 0, 0);
        }

        // epilogue -> om_lds; D-row quad*4+r <-> pixel wv*16+quad*4+r
        #pragma unroll
        for (int r = 0; r < 4; ++r) {
            int p_out = wv*16 + quad*4 + r;
            float* dst = &om_lds[p_out][0];
            dst[n] = c0[r] + boff[n];
            int o1 = 16 + n;
            if (o1 < 18) {
                dst[o1] = c1[r] + boff[o1];
            } else if (o1 < 27) {
                float z = c1[r] + bmsk[o1 - 18];
                dst[o1] = 1.f / (1.f + expf(-z));
            } else if (o1 == 27) {
                dst[27] = 0.f;
            }
        }
    }
    __syncthreads();   // win reads done; om_lds complete; samp may be reused

    // ---------------- deform phase (round-5 body; omp -> LDS) ----------------
    int pa = t >> 2, cg = t & 3;
    int ph = pa >> 3, pw = pa & 7;
    int h_a = h0 + ph, w_a = w0 + pw;
    const float* omp = &om_lds[pa][0];

    floatx4 acc[4];
    #pragma unroll
    for (int i = 0; i < 4; ++i) acc[i] = (floatx4){0.f,0.f,0.f,0.f};
    const ushort_t* wrow = wt + (wv*16 + n)*576 + quad*8;

    // params for phase 0 (taps 0..2)
    float dyv[3], dxv[3], mv[3];
    #pragma unroll
    for (int j = 0; j < 3; ++j) {
        dyv[j] = omp[2*j]; dxv[j] = omp[2*j+1]; mv[j] = omp[18+j];
    }

    #pragma unroll
    for (int p = 0; p < 3; ++p) {
        // preload this phase's 6 weight B-frags (complete under the gathers)
        bf16x8 wf[6];
        #pragma unroll
        for (int s = 0; s < 6; ++s)
            wf[s] = *(const bf16x8*)(wrow + (p*6 + s)*32);   // tap*64+half*32

        // ---------------- phase A: sample taps 3p..3p+2 ----------------
        #pragma unroll
        for (int kk = 0; kk < 3; ++kk) {
            // k = 3p + kk  =>  kr = p, kc = kk
            float py = (float)(h_a + p  - 1) + dyv[kk];
            float px = (float)(w_a + kk - 1) + dxv[kk];
            float y0f = floorf(py), x0f = floorf(px);
            float ly = py - y0f, lx = px - x0f;
            int y0 = (int)y0f, x0 = (int)x0f, y1 = y0 + 1, x1 = x0 + 1;
            float vy0 = ((unsigned)y0 < (unsigned)HH) ? 1.f : 0.f;
            float vy1 = ((unsigned)y1 < (unsigned)HH) ? 1.f : 0.f;
            float vx0 = ((unsigned)x0 < (unsigned)WW) ? 1.f : 0.f;
            float vx1 = ((unsigned)x1 < (unsigned)WW) ? 1.f : 0.f;
            float m   = mv[kk];

            float cw[4] = { (1.f-ly)*(1.f-lx)*vy0*vx0*m,
                            (1.f-ly)*lx      *vy0*vx1*m,
                            ly*(1.f-lx)      *vy1*vx0*m,
                            ly*lx            *vy1*vx1*m };
            int ys[4] = { y0, y0, y1, y1 };
            int xs[4] = { x0, x1, x0, x1 };

            // gather: 8 dwordx4, 4-lane clusters contiguous 128B (proven map)
            uint4 q[8];
            #pragma unroll
            for (int cn = 0; cn < 4; ++cn) {
                int yc = min(max(ys[cn], 0), HH-1);
                int xc = min(max(xs[cn], 0), WW-1);
                const uint4* cp = (const uint4*)(xbase + (((yc << 7) + xc) << 6) + cg*16);
                q[2*cn]   = cp[0];
                q[2*cn+1] = cp[1];
            }

            // packed fp32 corner accumulate
            f32x2 v2[8];
            {
                f32x2 w2; w2.x = cw[0]; w2.y = cw[0];
                unsigned u0[8] = { q[0].x, q[0].y, q[0].z, q[0].w,
                                   q[1].x, q[1].y, q[1].z, q[1].w };
                #pragma unroll
                for (int j = 0; j < 8; ++j) {
                    f32x2 f;
                    f.x = __uint_as_float(u0[j] << 16);
                    f.y = __uint_as_float(u0[j] & 0xffff0000u);
                    v2[j] = pk_mul(f, w2);
                }
            }
            #pragma unroll
            for (int cn = 1; cn < 4; ++cn) {
                f32x2 w2; w2.x = cw[cn]; w2.y = cw[cn];
                unsigned u0[8] = { q[2*cn].x, q[2*cn].y, q[2*cn].z, q[2*cn].w,
                                   q[2*cn+1].x, q[2*cn+1].y, q[2*cn+1].z, q[2*cn+1].w };
                #pragma unroll
                for (int j = 0; j < 8; ++j) {
                    f32x2 f;
                    f.x = __uint_as_float(u0[j] << 16);
                    f.y = __uint_as_float(u0[j] & 0xffff0000u);
                    v2[j] = pk_fma(f, w2, v2[j]);
                }
            }

            // pack 16 fp32 -> bf16, write 32B to samp[pa][kk*64 + cg*16]
            {
                unsigned uu[8];
                #pragma unroll
                for (int j = 0; j < 8; ++j)
                    uu[j] = cvt_pk_bf16(v2[j].x, v2[j].y);
                uint4* dst = (uint4*)(samp + pa*SROW + kk*64 + cg*16);
                dst[0] = make_uint4(uu[0], uu[1], uu[2], uu[3]);
                dst[1] = make_uint4(uu[4], uu[5], uu[6], uu[7]);
            }
        }

        // prefetch next phase's params before the barrier
        float dyn_[3], dxn_[3], mn_[3];
        if (p < 2) {
            #pragma unroll
            for (int j = 0; j < 3; ++j) {
                int k2 = 3*(p+1) + j;
                dyn_[j] = omp[2*k2]; dxn_[j] = omp[2*k2+1]; mn_[j] = omp[18+k2];
            }
        }

        __syncthreads();

        // ---------------- phase B: 24 MFMAs from LDS + reg weights ----------------
        #pragma unroll
        for (int kk = 0; kk < 3; ++kk) {
            #pragma unroll
            for (int half = 0; half < 2; ++half) {
                bf16x8 bfrag = wf[kk*2 + half];
                #pragma unroll
                for (int mt = 0; mt < 4; ++mt) {
                    bf16x8 afrag = *(const bf16x8*)(samp + (mt*16 + n)*SROW
                                                    + kk*64 + half*32 + quad*8);
                    acc[mt] = __builtin_amdgcn_mfma_f32_16x16x32_bf16(
                                  afrag, bfrag, acc[mt], 0, 0, 0);
                }
            }
        }

        if (p < 2) {
            __syncthreads();   // WAR: next phase A overwrites the buffer
            #pragma unroll
            for (int j = 0; j < 3; ++j) {
                dyv[j] = dyn_[j]; dxv[j] = dxn_[j]; mv[j] = mn_[j];
            }
        }
    }

    // store: out[b][o][h][w], o = wv*16 + n; D rows = local pixel id
    // p_local = mt*16 + quad*4 + r -> row = h0 + mt*2 + (quad>>1),
    //                                  col = w0 + (quad&1)*4 + r
    float* op = out + ((size_t)b*OO + (wv*16 + n))*HW;
    #pragma unroll
    for (int mt = 0; mt < 4; ++mt) {
        int row = h0 + mt*2 + (quad >> 1);
        int col = w0 + (quad & 1)*4;
        float4 st = make_float4(acc[mt][0], acc[mt][1], acc[mt][2], acc[mt][3]);
        *(float4*)(op + row*WW + col) = st;
    }
}

// ---------------------------------------------------------------------------
extern "C" void kernel_launch(void* const* d_in, const int* in_sizes, int n_in,
                              void* d_out, int out_size, void* d_ws, size_t ws_size,
                              hipStream_t stream)
{
    const float* x      = (const float*)d_in[0];
    const float* w_main = (const float*)d_in[1];
    const float* w_off  = (const float*)d_in[2];
    const float* b_off  = (const float*)d_in[3];
    const float* w_msk  = (const float*)d_in[4];
    const float* b_msk  = (const float*)d_in[5];
    float* out = (float*)d_out;

    unsigned char* ws = (unsigned char*)d_ws;
    ushort_t* xt = (ushort_t*)ws;
    ushort_t* wt = (ushort_t*)(ws + XT_BYTES + OM_BYTES);
    ushort_t* wb = (ushort_t*)(ws + XT_BYTES + OM_BYTES + WT_BYTES);

    // K1: transpose (4096 blocks) + repack (216 blocks) fused
    prep_kernel<<<4096 + 216, 256, 0, stream>>>(x, w_main, w_off, w_msk, xt, wt, wb);

    // K2: conv27 + deform fused
    conv_deform_kernel<<<NPIX/64, 256, 0, stream>>>(xt, wb, b_off, b_msk, wt, out);
}

// Round 8
// 163.697 us; speedup vs baseline: 1.0061x; 1.0061x over previous
//
#include <hip/hip_runtime.h>
#include <math.h>

#define BB 8
#define CC 64
#define OO 64
#define HH 128
#define WW 128
#define HW (HH*WW)              // 16384
#define NPIX (BB*HW)            // 131072

typedef __bf16 bf16x8 __attribute__((ext_vector_type(8)));
typedef float floatx4 __attribute__((ext_vector_type(4)));
typedef float f32x2 __attribute__((ext_vector_type(2)));
typedef unsigned short ushort_t;

// Workspace layout (bytes) — kept identical to prior rounds (om slot unused):
//  xt : bf16 NHWC [B][H][W][64]        16777216
//  om : (unused after fusion)          14680064
//  wt : bf16 [64][576]  (o, tap*64+c)     73728
//  wb : bf16 [32][576]  (o27pad, k)       36864
#define XT_BYTES  16777216
#define OM_BYTES  14680064
#define WT_BYTES  73728

__device__ __forceinline__ unsigned short f2b(float f) {
    unsigned u = __float_as_uint(f);
    u += 0x7fffu + ((u >> 16) & 1u);       // round-to-nearest-even
    return (unsigned short)(u >> 16);
}

// packed 2xf32 -> 2xbf16 in one VALU op (no builtin on gfx950; asm per guide)
__device__ __forceinline__ unsigned cvt_pk_bf16(float lo, float hi) {
    unsigned r;
    asm("v_cvt_pk_bf16_f32 %0, %1, %2" : "=v"(r) : "v"(lo), "v"(hi));
    return r;
}

__device__ __forceinline__ f32x2 pk_fma(f32x2 a, f32x2 b, f32x2 c) {
    f32x2 d;
    asm("v_pk_fma_f32 %0, %1, %2, %3" : "=v"(d) : "v"(a), "v"(b), "v"(c));
    return d;
}

__device__ __forceinline__ f32x2 pk_mul(f32x2 a, f32x2 b) {
    f32x2 d;
    asm("v_pk_mul_f32 %0, %1, %2" : "=v"(d) : "v"(a), "v"(b));
    return d;
}

// ---------------------------------------------------------------------------
// Kernel 1: FUSED prep — transpose (blocks 0..4095) + weight repack (4096..)
// Round-8: transpose loads vectorized to 2x float4/thread (was 8x scalar 4B).
// ---------------------------------------------------------------------------
__global__ __launch_bounds__(256) void prep_kernel(
    const float* __restrict__ x,
    const float* __restrict__ wm, const float* __restrict__ woff,
    const float* __restrict__ wmask,
    ushort_t* __restrict__ xt, ushort_t* __restrict__ wt,
    ushort_t* __restrict__ wb)
{
    __shared__ float tile[64][33];
    int bid = blockIdx.x;
    int t   = threadIdx.x;

    if (bid < 4096) {
        // ---- transpose: NCHW fp32 -> NHWC bf16 ----
        int bh = bid >> 2;
        int w0 = (bid & 3) * 32;
        int b  = bh >> 7;
        int h  = bh & 127;

        // load: thread t covers channel c = t>>2, 8 w's at wq*8
        {
            int c  = t >> 2;
            int wq = t & 3;
            const float* src = x + (((size_t)(b*CC + c))*HH + h)*WW + (w0 + wq*8);
            float4 v0 = ((const float4*)src)[0];
            float4 v1 = ((const float4*)src)[1];
            int wbse = wq*8;
            tile[c][wbse+0] = v0.x; tile[c][wbse+1] = v0.y;
            tile[c][wbse+2] = v0.z; tile[c][wbse+3] = v0.w;
            tile[c][wbse+4] = v1.x; tile[c][wbse+5] = v1.y;
            tile[c][wbse+6] = v1.z; tile[c][wbse+7] = v1.w;
        }
        __syncthreads();
        int tx = t & 31;
        int ty = t >> 5;
        #pragma unroll
        for (int j = 0; j < 4; ++j) {
            int w  = ty + 8*j;
            int cp = tx;
            unsigned u = cvt_pk_bf16(tile[2*cp][w], tile[2*cp+1][w]);
            *(unsigned*)(xt + (((size_t)(b*HH + h))*WW + (w0 + w))*CC + 2*cp) = u;
        }
    } else {
        // ---- weight repack to bf16 ----
        int i = (bid - 4096) * 256 + t;
        if (i < 36864) {
            int o = i / 576, k = i % 576, tap = k >> 6, c = k & 63;
            wt[i] = f2b(wm[o*576 + c*9 + tap]);
        }
        int j = i - 36864;
        if (j >= 0 && j < 18432) {
            int o = j / 576, k = j % 576, tap = k >> 6, c = k & 63;
            float v = 0.f;
            if (o < 18)      v = woff[o*576 + c*9 + tap];
            else if (o < 27) v = wmask[(o-18)*576 + c*9 + tap];
            wb[j] = f2b(v);
        }
    }
}

// ---------------------------------------------------------------------------
// Kernel 2: FUSED conv27 + deformable sampling + bf16 MFMA GEMM
//
// Round-8 change: ONE 12x12x64 LDS halo (20.7KB, zero-filled off-image)
// serves BOTH the conv A-fragments (inner 10x10) AND all 36 bilinear
// corner gathers per pixel. Deform phase A's 8 global loads/lane/tap
// (the dominant latency convoy: 63% stall cycles in round-7 PMC) become
// 8 ds_read_b128/lane/tap. Wave-uniform fallback to the original global
// path when any nonzero-weight corner leaves the halo (|offset|>~1;
// never for this problem's 0.05-scale offsets) keeps general correctness.
// Weight-zero corners clamp to an in-halo cell: staged values are always
// finite, so 0*v = 0 exactly. Numerics identical to the global path
// (same bf16 bits from xt).
// LDS: halo 20736 + samp 25600 + om_lds 7168 = 53504 B -> 3 blocks/CU.
// ---------------------------------------------------------------------------
#define SROW 200   // ushorts per pixel row: 3 taps * 64 ch + 8 pad
#define WROW 72    // halo cell stride: 64 ch + 8 pad (144B = 4-bank rotation)

__global__ __launch_bounds__(256, 3) void conv_deform_kernel(
    const ushort_t* __restrict__ xt, const ushort_t* __restrict__ wb,
    const float* __restrict__ boff, const float* __restrict__ bmsk,
    const ushort_t* __restrict__ wt, float* __restrict__ out)
{
    __shared__ ushort_t halo[144*WROW];  // 20736 B, 12x12 cells, lives whole kernel
    __shared__ ushort_t samp[64*SROW];   // 25600 B
    __shared__ float om_lds[64][28];     // 7168 B

    int t = threadIdx.x;
    int lane = t & 63, wv = t >> 6;
    int bid = blockIdx.x;
    int b  = bid >> 8;
    int th = (bid >> 4) & 15;
    int tw = bid & 15;
    int h0 = th * 8, w0 = tw * 8;

    const ushort_t* xbase = xt + ((size_t)b << 20);
    int n = lane & 15, quad = lane >> 4;

    // ---------------- stage 12x12 halo (rows h0-2..h0+9) ----------------
    for (int idx = t; idx < 1152; idx += 256) {
        int cell = idx >> 3;             // 0..143
        int ch   = (idx & 7) << 3;
        int cy = cell / 12, cx = cell - cy*12;
        int y = h0 + cy - 2, xx = w0 + cx - 2;
        uint4 val = make_uint4(0,0,0,0);
        if ((unsigned)y < (unsigned)HH && (unsigned)xx < (unsigned)WW)
            val = *(const uint4*)(xbase + (((y << 7) + xx) << 6) + ch);
        *(uint4*)(halo + cell*WROW + ch) = val;
    }
    __syncthreads();

    // ---------------- conv phase: 16 px x 32 outputs per wave ----------------
    {
        int p   = wv*16 + n;             // A-row n <-> pixel p
        int cph = p >> 3, cpw = p & 7;
        const ushort_t* wb0 = wb + n*576;
        const ushort_t* wb1 = wb + (16 + n)*576;
        floatx4 c0 = (floatx4){0.f,0.f,0.f,0.f};
        floatx4 c1 = (floatx4){0.f,0.f,0.f,0.f};

        #pragma unroll
        for (int s = 0; s < 18; ++s) {
            int tap  = s >> 1;
            int tr   = tap / 3, tc = tap % 3;
            int coff = (s & 1)*32 + quad*8;
            bf16x8 b0 = *(const bf16x8*)(wb0 + tap*64 + coff);
            bf16x8 b1 = *(const bf16x8*)(wb1 + tap*64 + coff);
            // halo cell: image row h0+cph+tr-1 -> halo row cph+tr+1
            bf16x8 a  = *(const bf16x8*)(halo + ((cph + tr + 1)*12 + (cpw + tc + 1))*WROW + coff);
            c0 = __builtin_amdgcn_mfma_f32_16x16x32_bf16(a, b0, c0, 0, 0, 0);
            c1 = __builtin_amdgcn_mfma_f32_16x16x32_bf16(a, b1, c1, 0, 0, 0);
        }

        // epilogue -> om_lds; D-row quad*4+r <-> pixel wv*16+quad*4+r
        #pragma unroll
        for (int r = 0; r < 4; ++r) {
            int p_out = wv*16 + quad*4 + r;
            float* dst = &om_lds[p_out][0];
            dst[n] = c0[r] + boff[n];
            int o1 = 16 + n;
            if (o1 < 18) {
                dst[o1] = c1[r] + boff[o1];
            } else if (o1 < 27) {
                float z = c1[r] + bmsk[o1 - 18];
                dst[o1] = 1.f / (1.f + expf(-z));
            } else if (o1 == 27) {
                dst[27] = 0.f;
            }
        }
    }
    __syncthreads();   // om_lds complete; halo stays read-only from here

    // ---------------- deform phase (3-tap phased; gathers from LDS halo) ----
    int pa = t >> 2, cg = t & 3;
    int ph = pa >> 3, pw = pa & 7;
    int h_a = h0 + ph, w_a = w0 + pw;
    const float* omp = &om_lds[pa][0];

    floatx4 acc[4];
    #pragma unroll
    for (int i = 0; i < 4; ++i) acc[i] = (floatx4){0.f,0.f,0.f,0.f};
    const ushort_t* wrow = wt + (wv*16 + n)*576 + quad*8;

    // params for phase 0 (taps 0..2)
    float dyv[3], dxv[3], mv[3];
    #pragma unroll
    for (int j = 0; j < 3; ++j) {
        dyv[j] = omp[2*j]; dxv[j] = omp[2*j+1]; mv[j] = omp[18+j];
    }

    #pragma unroll
    for (int p = 0; p < 3; ++p) {
        // preload this phase's 6 weight B-frags (complete under the gathers)
        bf16x8 wf[6];
        #pragma unroll
        for (int s = 0; s < 6; ++s)
            wf[s] = *(const bf16x8*)(wrow + (p*6 + s)*32);   // tap*64+half*32

        // ---------------- phase A: sample taps 3p..3p+2 ----------------
        #pragma unroll
        for (int kk = 0; kk < 3; ++kk) {
            // k = 3p + kk  =>  kr = p, kc = kk
            float py = (float)(h_a + p  - 1) + dyv[kk];
            float px = (float)(w_a + kk - 1) + dxv[kk];
            float y0f = floorf(py), x0f = floorf(px);
            float ly = py - y0f, lx = px - x0f;
            int y0 = (int)y0f, x0 = (int)x0f, y1 = y0 + 1, x1 = x0 + 1;
            float vy0 = ((unsigned)y0 < (unsigned)HH) ? 1.f : 0.f;
            float vy1 = ((unsigned)y1 < (unsigned)HH) ? 1.f : 0.f;
            float vx0 = ((unsigned)x0 < (unsigned)WW) ? 1.f : 0.f;
            float vx1 = ((unsigned)x1 < (unsigned)WW) ? 1.f : 0.f;
            float m   = mv[kk];

            float cw[4] = { (1.f-ly)*(1.f-lx)*vy0*vx0*m,
                            (1.f-ly)*lx      *vy0*vx1*m,
                            ly*(1.f-lx)      *vy1*vx0*m,
                            ly*lx            *vy1*vx1*m };
            int ys[4] = { y0, y0, y1, y1 };
            int xs[4] = { x0, x1, x0, x1 };

            // clamp to image; test halo residency (wave-uniform path select)
            int ycl[4], xcl[4], hidx[4];
            int ok = 1;
            #pragma unroll
            for (int cn = 0; cn < 4; ++cn) {
                int yc = min(max(ys[cn], 0), HH-1);
                int xc = min(max(xs[cn], 0), WW-1);
                ycl[cn] = yc; xcl[cn] = xc;
                int hy = yc - h0 + 2, hx = xc - w0 + 2;
                int inh = ((unsigned)hy < 12u) & ((unsigned)hx < 12u);
                ok &= ((cw[cn] == 0.f) | inh);
                hidx[cn] = min(max(hy, 0), 11)*12 + min(max(hx, 0), 11);
            }

            uint4 q[8];
            if (__all(ok)) {
                // fast path: gather from LDS halo (2x ds_read_b128/corner)
                #pragma unroll
                for (int cn = 0; cn < 4; ++cn) {
                    const uint4* cp = (const uint4*)(halo + hidx[cn]*WROW + cg*16);
                    q[2*cn]   = cp[0];
                    q[2*cn+1] = cp[1];
                }
            } else {
                // fallback: original global gather (correct for any offset)
                #pragma unroll
                for (int cn = 0; cn < 4; ++cn) {
                    const uint4* cp = (const uint4*)(xbase + (((ycl[cn] << 7) + xcl[cn]) << 6) + cg*16);
                    q[2*cn]   = cp[0];
                    q[2*cn+1] = cp[1];
                }
            }

            // packed fp32 corner accumulate
            f32x2 v2[8];
            {
                f32x2 w2; w2.x = cw[0]; w2.y = cw[0];
                unsigned u0[8] = { q[0].x, q[0].y, q[0].z, q[0].w,
                                   q[1].x, q[1].y, q[1].z, q[1].w };
                #pragma unroll
                for (int j = 0; j < 8; ++j) {
                    f32x2 f;
                    f.x = __uint_as_float(u0[j] << 16);
                    f.y = __uint_as_float(u0[j] & 0xffff0000u);
                    v2[j] = pk_mul(f, w2);
                }
            }
            #pragma unroll
            for (int cn = 1; cn < 4; ++cn) {
                f32x2 w2; w2.x = cw[cn]; w2.y = cw[cn];
                unsigned u0[8] = { q[2*cn].x, q[2*cn].y, q[2*cn].z, q[2*cn].w,
                                   q[2*cn+1].x, q[2*cn+1].y, q[2*cn+1].z, q[2*cn+1].w };
                #pragma unroll
                for (int j = 0; j < 8; ++j) {
                    f32x2 f;
                    f.x = __uint_as_float(u0[j] << 16);
                    f.y = __uint_as_float(u0[j] & 0xffff0000u);
                    v2[j] = pk_fma(f, w2, v2[j]);
                }
            }

            // pack 16 fp32 -> bf16, write 32B to samp[pa][kk*64 + cg*16]
            {
                unsigned uu[8];
                #pragma unroll
                for (int j = 0; j < 8; ++j)
                    uu[j] = cvt_pk_bf16(v2[j].x, v2[j].y);
                uint4* dst = (uint4*)(samp + pa*SROW + kk*64 + cg*16);
                dst[0] = make_uint4(uu[0], uu[1], uu[2], uu[3]);
                dst[1] = make_uint4(uu[4], uu[5], uu[6], uu[7]);
            }
        }

        // prefetch next phase's params before the barrier
        float dyn_[3], dxn_[3], mn_[3];
        if (p < 2) {
            #pragma unroll
            for (int j = 0; j < 3; ++j) {
                int k2 = 3*(p+1) + j;
                dyn_[j] = omp[2*k2]; dxn_[j] = omp[2*k2+1]; mn_[j] = omp[18+k2];
            }
        }

        __syncthreads();

        // ---------------- phase B: 24 MFMAs from LDS + reg weights ----------------
        #pragma unroll
        for (int kk = 0; kk < 3; ++kk) {
            #pragma unroll
            for (int half = 0; half < 2; ++half) {
                bf16x8 bfrag = wf[kk*2 + half];
                #pragma unroll
                for (int mt = 0; mt < 4; ++mt) {
                    bf16x8 afrag = *(const bf16x8*)(samp + (mt*16 + n)*SROW
                                                    + kk*64 + half*32 + quad*8);
                    acc[mt] = __builtin_amdgcn_mfma_f32_16x16x32_bf16(
                                  afrag, bfrag, acc[mt], 0, 0, 0);
                }
            }
        }

        if (p < 2) {
            __syncthreads();   // WAR: next phase A overwrites samp
            #pragma unroll
            for (int j = 0; j < 3; ++j) {
                dyv[j] = dyn_[j]; dxv[j] = dxn_[j]; mv[j] = mn_[j];
            }
        }
    }

    // store: out[b][o][h][w], o = wv*16 + n; D rows = local pixel id
    // p_local = mt*16 + quad*4 + r -> row = h0 + mt*2 + (quad>>1),
    //                                  col = w0 + (quad&1)*4 + r
    float* op = out + ((size_t)b*OO + (wv*16 + n))*HW;
    #pragma unroll
    for (int mt = 0; mt < 4; ++mt) {
        int row = h0 + mt*2 + (quad >> 1);
        int col = w0 + (quad & 1)*4;
        float4 st = make_float4(acc[mt][0], acc[mt][1], acc[mt][2], acc[mt][3]);
        *(float4*)(op + row*WW + col) = st;
    }
}

// ---------------------------------------------------------------------------
extern "C" void kernel_launch(void* const* d_in, const int* in_sizes, int n_in,
                              void* d_out, int out_size, void* d_ws, size_t ws_size,
                              hipStream_t stream)
{
    const float* x      = (const float*)d_in[0];
    const float* w_main = (const float*)d_in[1];
    const float* w_off  = (const float*)d_in[2];
    const float* b_off  = (const float*)d_in[3];
    const float* w_msk  = (const float*)d_in[4];
    const float* b_msk  = (const float*)d_in[5];
    float* out = (float*)d_out;

    unsigned char* ws = (unsigned char*)d_ws;
    ushort_t* xt = (ushort_t*)ws;
    ushort_t* wt = (ushort_t*)(ws + XT_BYTES + OM_BYTES);
    ushort_t* wb = (ushort_t*)(ws + XT_BYTES + OM_BYTES + WT_BYTES);

    // K1: transpose (4096 blocks) + repack (216 blocks) fused
    prep_kernel<<<4096 + 216, 256, 0, stream>>>(x, w_main, w_off, w_msk, xt, wt, wb);

    // K2: conv27 + deform fused, LDS-halo gathers
    conv_deform_kernel<<<NPIX/64, 256, 0, stream>>>(xt, wb, b_off, b_msk, wt, out);
}